// Round 7
// baseline (195.918 us; speedup 1.0000x reference)
//
#include <hip/hip_runtime.h>
#include <hip/hip_bf16.h>

// Sizes (fixed by the problem)
#define HDIM 512
#define BB 32
#define SS 4096
#define TR 64                  // rows per block
#define NCH (SS/TR)            // 64 chunks per b
#define NBLK (BB*NCH)          // 2048 blocks

typedef __attribute__((ext_vector_type(8))) short short8;   // 8 x bf16
typedef __attribute__((ext_vector_type(4))) float f32x4;

// Workspace layout (bytes)
#define WS_QB    0                        // 32*512*4 = 65536
#define WS_WRBF  65536                    // 512*512*2 = 524288 (fragment-major)
#define WS_PM    (65536+524288)           // 2048*4 (16KB region)
#define WS_PD    (WS_PM+16384)            // 2048*4 (16KB region)
#define WS_PU    (WS_PD+16384)            // 2048*512*4 = 4MB

__device__ __forceinline__ unsigned short f2bf(float f){
  unsigned u = __float_as_uint(f);
  u += 0x7FFFu + ((u >> 16) & 1u);        // RNE
  return (unsigned short)(u >> 16);
}

__device__ __forceinline__ float fast_tanh(float x){
  float e = __expf(2.f * x);
  return 1.f - __fdividef(2.f, 1.f + e);
}

// ---------------- K1: prep (fused) ----------------
// blocks 0..127 : fragment-major bf16 Wr:
//   frag id f = (t16*16 + kt)*64 + lane holds Wr[t16*16+(lane&15)][kt*32+(lane>>4)*8 ..+8]
//   -> k_main B-frag load = ONE contiguous 1KB wave load.
// blocks 128..159: qb[b,h] = bq[h] + br[h] + query[b,:] . Wq[h,:]
__global__ __launch_bounds__(256) void k_prep(const float* __restrict__ Wr,
                                              unsigned short* __restrict__ wrbF,
                                              const float* __restrict__ query,
                                              const float* __restrict__ Wq,
                                              const float* __restrict__ bq,
                                              const float* __restrict__ br,
                                              float* __restrict__ qb){
  int t = threadIdx.x;
  if (blockIdx.x < 128){
    int gid = blockIdx.x*256 + t;        // [0, 32768)
    int lane = gid & 63;
    int tile = gid >> 6;                 // [0,512): kt = tile&15, t16 = tile>>4
    int kt = tile & 15, t16 = tile >> 4;
    int col = t16*16 + (lane & 15);
    int k0  = kt*32 + (lane >> 4)*8;
    const float* src = Wr + (size_t)col*HDIM + k0;
    f32x4 v0 = *(const f32x4*)(src);
    f32x4 v1 = *(const f32x4*)(src + 4);
    ushort4 o0, o1;
    o0.x = f2bf(v0.x); o0.y = f2bf(v0.y); o0.z = f2bf(v0.z); o0.w = f2bf(v0.w);
    o1.x = f2bf(v1.x); o1.y = f2bf(v1.y); o1.z = f2bf(v1.z); o1.w = f2bf(v1.w);
    ushort* dst = wrbF + (size_t)gid*8;
    *(ushort4*)(dst)     = o0;
    *(ushort4*)(dst + 4) = o1;
  } else {
    __shared__ __align__(16) float sq[HDIM];
    int b = blockIdx.x - 128;
    sq[t] = query[b*HDIM + t];
    sq[t+256] = query[b*HDIM + t + 256];
    __syncthreads();
    const f32x4* sq4 = (const f32x4*)sq;
    for (int hh = 0; hh < 2; ++hh){
      int h = t + hh*256;
      const f32x4* w4 = (const f32x4*)(Wq + (size_t)h*HDIM);
      float acc = bq[h] + br[h];
      #pragma unroll 4
      for (int k = 0; k < HDIM/4; ++k){
        f32x4 w = w4[k]; f32x4 q = sq4[k];
        acc += w.x*q.x + w.y*q.y + w.z*q.z + w.w*q.w;
      }
      qb[b*HDIM + h] = acc;
    }
  }
}

// ---------------- K2: main fused kernel ----------------
// 2048 blocks x 512 thr (8 waves), 64-row tile, ~76KB LDS -> 2 blocks/CU.
// A-layout in LDS: element (row,k) at byte row*1024 + (2k ^ ((row&7)<<4)).
// Key identity: (kt*64 + g*16) ^ ((row&7)<<4)
//             = (kt ^ b)*64 + (g*16 ^ ((row&3)<<4)),  b = (row>>2)&1
// so A-reads use two thread-uniform bases (even/odd kt) + immediate offsets.
__global__ __launch_bounds__(512, 4) void k_main(const float* __restrict__ ref,
                                                 const unsigned short* __restrict__ wrbF,
                                                 const float* __restrict__ qb,
                                                 const float* __restrict__ V,
                                                 float* __restrict__ pm,
                                                 float* __restrict__ pd,
                                                 float* __restrict__ pu){
  int bid = blockIdx.x;
  int b = bid >> 6;
  int chunk = bid & 63;
  int tid = threadIdx.x;
  int w = tid >> 6, lane = tid & 63;
  int lo16 = lane & 15, g = lane >> 4;

  __shared__ __align__(16) unsigned short sA[TR*HDIM]; // 64KB swizzled bf16
  __shared__ __align__(16) float sQb[HDIM];
  __shared__ __align__(16) float sV[HDIM];
  __shared__ float sLog[8][TR];
  __shared__ float sE[TR];
  __shared__ __align__(16) float sUa[2][HDIM];

  sQb[tid] = qb[b*HDIM + tid];
  sV[tid]  = V[tid];

  // ---- stage A: 64 rows x 512 f32 = 8192 f32x4; 16 per thread ----
  {
    const f32x4* s4 = (const f32x4*)(ref + ((size_t)b*SS + (size_t)chunk*TR)*HDIM) + tid;
    f32x4 R[16];
    #pragma unroll
    for (int i = 0; i < 16; ++i) R[i] = s4[512*i];
    #pragma unroll
    for (int i = 0; i < 16; ++i){
      int idx = tid + 512*i;
      int row = idx >> 7, c4 = idx & 127;
      f32x4 v = R[i];
      ushort4 o;
      o.x = f2bf(v.x); o.y = f2bf(v.y); o.z = f2bf(v.z); o.w = f2bf(v.w);
      unsigned byte = (unsigned)(row*1024) + (((unsigned)c4*8) ^ ((unsigned)(row & 7) << 4));
      *(ushort4*)((char*)sA + byte) = o;
    }
  }
  __syncthreads();

  // ---- GEMM + logits: wave covers cols [w*64, w*64+64), rows 0..63 ----
  // A-read bases (thread-uniform across m and kt):
  unsigned baseA = (unsigned)(lo16*1024) + (((unsigned)g*16) ^ ((unsigned)(lo16 & 3) << 4));
  unsigned bsel  = (unsigned)((lo16 >> 2) & 1) * 64u;
  const char* pAe = (const char*)sA + baseA + bsel;   // even kt
  const char* pAo = (const char*)sA + baseA - bsel + 64; // odd kt: base-b*64, +64 folded below
  // note: odd-kt addr = baseA - bsel + kt*64; write as (pAo + (kt-1)*64)

  float lacc[4][4];
  #pragma unroll
  for (int m = 0; m < 4; ++m)
    #pragma unroll
    for (int r = 0; r < 4; ++r)
      lacc[m][r] = 0.f;

  #pragma unroll
  for (int nh = 0; nh < 2; ++nh){
    const short8* wfp = (const short8*)wrbF + ((size_t)(w*4 + nh*2)*16*64 + lane);
    f32x4 acc[4][2];
    #pragma unroll
    for (int m = 0; m < 4; ++m)
      #pragma unroll
      for (int n = 0; n < 2; ++n)
        acc[m][n] = (f32x4){0.f, 0.f, 0.f, 0.f};

    #pragma unroll
    for (int kt = 0; kt < 16; ++kt){
      short8 af[4];
      #pragma unroll
      for (int m = 0; m < 4; ++m){
        if (kt & 1)
          af[m] = *(const short8*)(pAo + (m*16384 + (kt-1)*64));
        else
          af[m] = *(const short8*)(pAe + (m*16384 + kt*64));
      }
      short8 bfr[2];
      bfr[0] = wfp[kt*64];
      bfr[1] = wfp[1024 + kt*64];
      #pragma unroll
      for (int m = 0; m < 4; ++m)
        #pragma unroll
        for (int n = 0; n < 2; ++n)
          acc[m][n] = __builtin_amdgcn_mfma_f32_16x16x32_bf16(af[m], bfr[n], acc[m][n], 0, 0, 0);
    }

    // epilogue: D-layout col=lane&15, row=16m+4g+r
    #pragma unroll
    for (int n = 0; n < 2; ++n){
      int col = w*64 + nh*32 + n*16 + lo16;
      float qv = sQb[col], vv = sV[col];
      #pragma unroll
      for (int m = 0; m < 4; ++m)
        #pragma unroll
        for (int r = 0; r < 4; ++r){
          float x = qv + acc[m][n][r];
          lacc[m][r] += vv * fast_tanh(x);
        }
    }
  }

  // reduce over 16 lanes (cols) -> logit partials for rows 16m+4g+r
  #pragma unroll
  for (int m = 0; m < 4; ++m)
    #pragma unroll
    for (int r = 0; r < 4; ++r){
      float v = lacc[m][r];
      v += __shfl_xor(v, 1); v += __shfl_xor(v, 2);
      v += __shfl_xor(v, 4); v += __shfl_xor(v, 8);
      lacc[m][r] = v;
    }
  if (lo16 == 0){
    #pragma unroll
    for (int m = 0; m < 4; ++m)
      #pragma unroll
      for (int r = 0; r < 4; ++r)
        sLog[w][16*m + 4*g + r] = lacc[m][r];
  }
  __syncthreads();

  // ---- chunk softmax partials (wave 0; 64 lanes = 64 rows) ----
  if (w == 0){
    float l = sLog[0][lane] + sLog[1][lane] + sLog[2][lane] + sLog[3][lane]
            + sLog[4][lane] + sLog[5][lane] + sLog[6][lane] + sLog[7][lane];
    float mx = l;
    mx = fmaxf(mx, __shfl_xor(mx, 1));  mx = fmaxf(mx, __shfl_xor(mx, 2));
    mx = fmaxf(mx, __shfl_xor(mx, 4));  mx = fmaxf(mx, __shfl_xor(mx, 8));
    mx = fmaxf(mx, __shfl_xor(mx, 16)); mx = fmaxf(mx, __shfl_xor(mx, 32));
    float e = __expf(l - mx);
    float d = e;
    d += __shfl_xor(d, 1); d += __shfl_xor(d, 2); d += __shfl_xor(d, 4);
    d += __shfl_xor(d, 8); d += __shfl_xor(d, 16); d += __shfl_xor(d, 32);
    sE[lane] = e;
    if (lane == 0){ pm[bid] = mx; pd[bid] = d; }
  }
  __syncthreads();

  // ---- u[k] = sum_s e_s * A[s,k]; half-split: h=rows 32h..32h+31, k=2*t8,2*t8+1 ----
  {
    int h = tid >> 8, t8 = tid & 255;
    const char* sAB = (const char*)sA + (unsigned)h*32768u;
    unsigned b0 = (unsigned)(4*t8);
    // 8 bases: byte = (4*t8) ^ (j<<4), j = s&7
    const char* bj[8];
    #pragma unroll
    for (int j = 0; j < 8; ++j) bj[j] = sAB + (b0 ^ ((unsigned)j << 4));
    const float* eh = sE + h*32;
    float u0 = 0.f, u1 = 0.f;
    #pragma unroll
    for (int s2 = 0; s2 < 32; ++s2){
      unsigned pk = *(const unsigned*)(bj[s2 & 7] + s2*1024);
      float e = eh[s2];
      u0 += e * __uint_as_float((pk & 0xFFFFu) << 16);
      u1 += e * __uint_as_float(pk & 0xFFFF0000u);
    }
    sUa[h][2*t8]     = u0;
    sUa[h][2*t8 + 1] = u1;
  }
  __syncthreads();
  pu[(size_t)bid*HDIM + tid] = sUa[0][tid] + sUa[1][tid];
}

// ---------------- K3: combine 64 partials per b + out = Wr @ u + br ----------------
__global__ __launch_bounds__(256) void k_final(const float* __restrict__ Wr,
                                               const float* __restrict__ br,
                                               const float* __restrict__ pm,
                                               const float* __restrict__ pd,
                                               const float* __restrict__ pu,
                                               float* __restrict__ out){
  int b = blockIdx.x, t = threadIdx.x, lane = t & 63, w = t >> 6;
  __shared__ float sSc[NCH];
  __shared__ __align__(16) float sU[HDIM];
  __shared__ float sMD0;

  if (w == 0){
    float m = pm[b*NCH + lane];
    float mx = m;
    mx = fmaxf(mx, __shfl_xor(mx, 1));  mx = fmaxf(mx, __shfl_xor(mx, 2));
    mx = fmaxf(mx, __shfl_xor(mx, 4));  mx = fmaxf(mx, __shfl_xor(mx, 8));
    mx = fmaxf(mx, __shfl_xor(mx, 16)); mx = fmaxf(mx, __shfl_xor(mx, 32));
    float sc = __expf(m - mx);
    float d = sc * pd[b*NCH + lane];
    d += __shfl_xor(d, 1); d += __shfl_xor(d, 2); d += __shfl_xor(d, 4);
    d += __shfl_xor(d, 8); d += __shfl_xor(d, 16); d += __shfl_xor(d, 32);
    sSc[lane] = sc;
    if (lane == 0) sMD0 = d;
  }
  __syncthreads();

  float inv = 1.f / sMD0;
  float u0 = 0.f, u1 = 0.f;
  for (int c = 0; c < NCH; ++c){
    float sc = sSc[c];
    const float* p = pu + ((size_t)(b*NCH + c))*HDIM;
    u0 += sc * p[t];
    u1 += sc * p[t+256];
  }
  sU[t]     = u0 * inv;
  sU[t+256] = u1 * inv;
  __syncthreads();

  const f32x4* su4 = (const f32x4*)sU;
  for (int hh = 0; hh < 2; ++hh){
    int h = t + hh*256;
    const f32x4* w4 = (const f32x4*)(Wr + (size_t)h*HDIM);
    float acc = br[h];
    #pragma unroll 4
    for (int k = 0; k < HDIM/4; ++k){
      f32x4 wv = w4[k], uv = su4[k];
      acc += wv.x*uv.x + wv.y*uv.y + wv.z*uv.z + wv.w*uv.w;
    }
    out[b*HDIM + h] = acc;
  }
}

extern "C" void kernel_launch(void* const* d_in, const int* in_sizes, int n_in,
                              void* d_out, int out_size, void* d_ws, size_t ws_size,
                              hipStream_t stream){
  const float* query = (const float*)d_in[0];
  const float* ref   = (const float*)d_in[1];
  const float* Wq    = (const float*)d_in[2];
  const float* bq    = (const float*)d_in[3];
  const float* Wr    = (const float*)d_in[4];
  const float* br    = (const float*)d_in[5];
  const float* V     = (const float*)d_in[6];
  char* ws = (char*)d_ws;
  float*          qbv  = (float*)(ws + WS_QB);
  unsigned short* wrbF = (unsigned short*)(ws + WS_WRBF);
  float*          pm   = (float*)(ws + WS_PM);
  float*          pd   = (float*)(ws + WS_PD);
  float*          pu   = (float*)(ws + WS_PU);
  float* out = (float*)d_out;

  k_prep<<<dim3(160), dim3(256), 0, stream>>>(Wr, wrbF, query, Wq, bq, br, qbv);
  k_main<<<dim3(NBLK), dim3(512), 0, stream>>>(ref, wrbF, qbv, V, pm, pd, pu);
  k_final<<<dim3(BB), dim3(256), 0, stream>>>(Wr, br, pm, pd, pu, out);
}